// Round 7
// baseline (2312.445 us; speedup 1.0000x reference)
//
#include <hip/hip_runtime.h>
#include <stdint.h>

#define NN    100000
#define EE    400000
#define NNZK  800000
#define ADJK  400000
#define DDIM  100
#define DOUTK 300

typedef unsigned short u16;
typedef unsigned int   u32;
typedef __attribute__((ext_vector_type(8))) short short8;
typedef __attribute__((ext_vector_type(4))) float f32x4;
typedef __attribute__((ext_vector_type(4))) unsigned short u16x4;

__device__ __forceinline__ float bf2f(u16 b) { return __uint_as_float(((u32)b) << 16); }
__device__ __forceinline__ u16 f2bf(float x) {
    u32 u = __float_as_uint(x);
    u32 r = (u + 0x7FFFu + ((u >> 16) & 1u)) >> 16;  // RNE
    return (u16)r;
}
// truncation hi/lo split: x ~= bf(hi) + bf(lo) to ~2^-17 rel
__device__ __forceinline__ void split_hl(float x, u16& h, u16& l) {
    u32 u = __float_as_uint(x);
    h = (u16)(u >> 16);
    float hf = __uint_as_float(u & 0xFFFF0000u);
    l = (u16)(__float_as_uint(x - hf) >> 16);
}

// ================= CSR building (int atomics only) =================

__global__ __launch_bounds__(256) void k_count(
    const int* __restrict__ idx, int* __restrict__ cnt, int nnz, int kmax)
{
    int i = blockIdx.x * 256 + threadIdx.x;
    if (i >= nnz) return;
    int key = idx[2 * i];
    if (key < 0 || key >= kmax) return;
    atomicAdd(&cnt[key], 1);
}

__global__ __launch_bounds__(256) void k_alloc(
    const int* __restrict__ cnt, int* __restrict__ base, int* __restrict__ cur,
    int* __restrict__ ctr, int n)
{
    int i = blockIdx.x * 256 + threadIdx.x;
    int lane = threadIdx.x & 63;
    int c = (i < n) ? cnt[i] : 0;
    int s = c;
#pragma unroll
    for (int m = 1; m < 64; m <<= 1) {
        int t = __shfl_up(s, m, 64);
        if (lane >= m) s += t;
    }
    int total = __shfl(s, 63, 64);
    int wbase = 0;
    if (lane == 63) wbase = atomicAdd(ctr, total);
    wbase = __shfl(wbase, 63, 64);
    int b = wbase + s - c;   // exclusive within wave
    if (i < n) { base[i] = b; cur[i] = b; }
}

__global__ __launch_bounds__(256) void k_fill(
    const int* __restrict__ idx, const float* __restrict__ val, int* __restrict__ cur,
    int* __restrict__ ocol, float* __restrict__ oval, int* __restrict__ opos,
    int nnz, int kmax)
{
    int i = blockIdx.x * 256 + threadIdx.x;
    if (i >= nnz) return;
    int key = idx[2 * i];
    if (key < 0 || key >= kmax) return;
    int p = atomicAdd(&cur[key], 1);
    ocol[p] = idx[2 * i + 1];
    if (oval) oval[p] = val[i];
    if (opos) opos[i] = p;
}

// ================= rels build + fused attention logits =================
// ONE 32-LANE GROUP PER EDGE (8 edges/block): 4 dims/lane, lanes 0..24 active.
__global__ __launch_bounds__(256) void rels_build(
    const int* __restrict__ base, const int* __restrict__ cnt,
    const int* __restrict__ rk, const float* __restrict__ rv,
    const int* __restrict__ epos, const int* __restrict__ adjr,
    const float* __restrict__ emb, u16* __restrict__ rels,
    const float* __restrict__ attnA, float* __restrict__ attA0, float* __restrict__ attA1,
    float* __restrict__ denA0, float* __restrict__ denA1,
    const float* __restrict__ attnB, float* __restrict__ attB0, float* __restrict__ attB1,
    float* __restrict__ denB0, float* __restrict__ denB1,
    int kMax, int nE)
{
    int e = blockIdx.x * 8 + (threadIdx.x >> 5);
    if (e >= nE) return;
    int gl = threadIdx.x & 31;
    bool act = gl < 25;
    int d4 = gl * 4;
    int st = base[e], k = cnt[e];
    bool hasB = (attnB != nullptr);

    float4 acc = {0.f, 0.f, 0.f, 0.f};
    for (int j = 0; j < k; ++j) {
        int kk = rk[st + j];
        if (kk < 0 || kk >= kMax) continue;
        float v = rv[st + j];
        if (act) {
            float4 ev = *(const float4*)(emb + (size_t)kk * DDIM + d4);
            acc.x += v * ev.x; acc.y += v * ev.y;
            acc.z += v * ev.z; acc.w += v * ev.w;
        }
    }
    float4 aA0 = {0.f,0.f,0.f,0.f}, aA1 = {0.f,0.f,0.f,0.f};
    float4 aB0 = {0.f,0.f,0.f,0.f}, aB1 = {0.f,0.f,0.f,0.f};
    if (act) {
        aA0 = *(const float4*)(attnA + d4);
        aA1 = *(const float4*)(attnA + DDIM + d4);
        if (hasB) {
            aB0 = *(const float4*)(attnB + d4);
            aB1 = *(const float4*)(attnB + DDIM + d4);
        }
    }
    float s   = acc.x*acc.x + acc.y*acc.y + acc.z*acc.z + acc.w*acc.w;
    float dA0 = acc.x*aA0.x + acc.y*aA0.y + acc.z*aA0.z + acc.w*aA0.w;
    float dA1 = acc.x*aA1.x + acc.y*aA1.y + acc.z*aA1.z + acc.w*aA1.w;
#pragma unroll
    for (int m = 1; m <= 16; m <<= 1) {   // masks < 32: stays within the 32-group
        s   += __shfl_xor(s, m, 64);
        dA0 += __shfl_xor(dA0, m, 64);
        dA1 += __shfl_xor(dA1, m, 64);
    }
    float dB0 = 0.f, dB1 = 0.f;
    if (hasB) {
        dB0 = acc.x*aB0.x + acc.y*aB0.y + acc.z*aB0.z + acc.w*aB0.w;
        dB1 = acc.x*aB1.x + acc.y*aB1.y + acc.z*aB1.z + acc.w*aB1.w;
#pragma unroll
        for (int m = 1; m <= 16; m <<= 1) {
            dB0 += __shfl_xor(dB0, m, 64);
            dB1 += __shfl_xor(dB1, m, 64);
        }
    }
    float sc = 1.f / fmaxf(sqrtf(s), 1e-12f);
    int ep = epos[e];
    if (act) {
        u16x4 pk;
        pk[0] = f2bf(acc.x * sc); pk[1] = f2bf(acc.y * sc);
        pk[2] = f2bf(acc.z * sc); pk[3] = f2bf(acc.w * sc);
        *(u16x4*)(rels + (size_t)ep * DDIM + d4) = pk;
    }
    if (gl == 0) {
        int row = adjr[2 * e];
        bool rok = (row >= 0 && row < NN);
        float eA0 = __expf(dA0 * sc), eA1 = __expf(dA1 * sc);
        attA0[ep] = eA0; attA1[ep] = eA1;
        if (rok) { atomicAdd(&denA0[row], eA0); atomicAdd(&denA1[row], eA1); }
        if (hasB) {
            float eB0 = __expf(dB0 * sc), eB1 = __expf(dB1 * sc);
            attB0[ep] = eB0; attB1[ep] = eB1;
            if (rok) { atomicAdd(&denB0[row], eB0); atomicAdd(&denB1[row], eB1); }
        }
    }
}

// ================= fold 1/den into att (per-row, CSR-contiguous) =============
__global__ __launch_bounds__(256) void att_fold(
    const int* __restrict__ base, const int* __restrict__ cnt,
    float* __restrict__ a0, float* __restrict__ a1,
    const float* __restrict__ d0, const float* __restrict__ d1,
    float* __restrict__ b0, float* __restrict__ b1,
    const float* __restrict__ e0, const float* __restrict__ e1, int nRows)
{
    int i = blockIdx.x * 256 + threadIdx.x;
    if (i >= nRows) return;
    int st = base[i], k = cnt[i];
    float v0 = d0[i], v1 = d1[i];
    float i0 = (v0 > 0.f) ? 1.f / v0 : 0.f;
    float i1 = (v1 > 0.f) ? 1.f / v1 : 0.f;
    float i2 = 0.f, i3 = 0.f;
    if (b0) {
        float w0 = e0[i], w1 = e1[i];
        i2 = (w0 > 0.f) ? 1.f / w0 : 0.f;
        i3 = (w1 > 0.f) ? 1.f / w1 : 0.f;
    }
    for (int j = 0; j < k; ++j) {
        a0[st + j] *= i0;
        a1[st + j] *= i1;
        if (b0) { b0[st + j] *= i2; b1[st + j] *= i3; }
    }
}

// ================= feature mean-aggregation gather (fused tanh) ==============
// ONE 32-LANE GROUP PER ROW (8 rows/block): 4 dims/lane, lanes 0..24 active.
__global__ __launch_bounds__(256) void feat_gather(
    const int* __restrict__ base, const int* __restrict__ cnt, const int* __restrict__ fcol,
    const float* __restrict__ emb, float* __restrict__ dst, int colMax, int nRows)
{
    int w = blockIdx.x * 8 + (threadIdx.x >> 5);
    if (w >= nRows) return;
    int gl = threadIdx.x & 31;
    bool act = gl < 25;
    int d4 = gl * 4;
    int st = base[w], k = cnt[w];
    float4 acc = {0.f, 0.f, 0.f, 0.f};
    for (int j = 0; j < k; ++j) {
        int col = fcol[st + j];
        if (col < 0 || col >= colMax) continue;
        if (act) {
            float4 ev = *(const float4*)(emb + (size_t)col * DDIM + d4);
            acc.x += ev.x; acc.y += ev.y; acc.z += ev.z; acc.w += ev.w;
        }
    }
    float inv = k ? 1.f / (float)k : 0.f;
    if (act) {
        float4 o;
        o.x = tanhf(acc.x * inv); o.y = tanhf(acc.y * inv);
        o.z = tanhf(acc.z * inv); o.w = tanhf(acc.w * inv);
        *(float4*)(dst + (size_t)w * DOUTK + d4) = o;
    }
}

// ================= message-passing layer (gather, pre-normalized att) =========
// one wave per row; TWO EDGES PER LOOP STEP (one per 32-lane group, 4 dims/lane)
__global__ __launch_bounds__(256) void mp_layer(
    const int* __restrict__ base, const int* __restrict__ cnt, const int* __restrict__ ecol,
    const u16* __restrict__ rels, const float* __restrict__ att,
    const float* __restrict__ src, float* __restrict__ dst, int nRows)
{
    int w = blockIdx.x * 4 + (threadIdx.x >> 6);
    if (w >= nRows) return;
    int lane = threadIdx.x & 63;
    int g = lane >> 5, gl = lane & 31;
    bool act = gl < 25;
    int d4 = gl * 4;
    int st = base[w], k = cnt[w];
    float4 acc = {0.f, 0.f, 0.f, 0.f};
    for (int j = 0; j < k; j += 2) {
        int je = j + g;
        int col = -1;
        if (je < k) col = ecol[st + je];
        bool cok = (col >= 0 && col < NN);
        float4 r = {0.f,0.f,0.f,0.f}, f = {0.f,0.f,0.f,0.f};
        if (cok && act) {
            u16x4 rr = *(const u16x4*)(rels + (size_t)(st + je) * DDIM + d4);
            r.x = bf2f(rr[0]); r.y = bf2f(rr[1]);
            r.z = bf2f(rr[2]); r.w = bf2f(rr[3]);
            f = *(const float4*)(src + (size_t)col * DOUTK + d4);
        }
        float pd = f.x*r.x + f.y*r.y + f.z*r.z + f.w*r.w;
#pragma unroll
        for (int m = 1; m <= 16; m <<= 1) pd += __shfl_xor(pd, m, 64);  // within-group
        float a = cok ? att[st + je] : 0.f;
        float c2 = 2.f * pd;
        acc.x += a * (f.x - c2 * r.x);
        acc.y += a * (f.y - c2 * r.y);
        acc.z += a * (f.z - c2 * r.z);
        acc.w += a * (f.w - c2 * r.w);
    }
    // combine the two groups' partial sums (even edges + odd edges)
    acc.x += __shfl_xor(acc.x, 32, 64);
    acc.y += __shfl_xor(acc.y, 32, 64);
    acc.z += __shfl_xor(acc.z, 32, 64);
    acc.w += __shfl_xor(acc.w, 32, 64);
    if (g == 0 && act) {
        float4 o;
        o.x = tanhf(acc.x); o.y = tanhf(acc.y);
        o.z = tanhf(acc.z); o.w = tanhf(acc.w);
        *(float4*)(dst + (size_t)w * DOUTK + d4) = o;
    }
}

// ---- inverse norms of proxy rows ----
__global__ __launch_bounds__(64) void proxy_norms(const float* __restrict__ proxy, float* __restrict__ pn)
{
    int k = threadIdx.x;
    if (k >= 64) return;
    float s = 0.f;
    for (int i = 0; i < DOUTK; ++i) { float v = proxy[k * DOUTK + i]; s += v * v; }
    pn[k] = 1.f / fmaxf(sqrtf(s), 1e-12f);
}

// ---- weight prepack kernels: fp32 -> frag-order bf16 [ktile][n][8] ----
__global__ __launch_bounds__(256) void pack_proxyT(const float* __restrict__ p, u16* __restrict__ o)
{
    int t = blockIdx.x * 256 + threadIdx.x;
    if (t >= 40 * 64 * 8) return;
    int j = t & 7, n = (t >> 3) & 63, kt = t >> 9;
    int k = kt * 8 + j;
    o[t] = f2bf((k < 300) ? p[n * 300 + k] : 0.f);
}
__global__ __launch_bounds__(256) void pack_proxyB(const float* __restrict__ p, u16* __restrict__ o)
{
    int t = blockIdx.x * 256 + threadIdx.x;
    if (t >= 8 * 304 * 8) return;
    int j = t & 7, n = (t >> 3) % 304, kt = t / (304 * 8);
    int k = kt * 8 + j;
    o[t] = f2bf((k < 64 && n < 300) ? p[k * 300 + n] : 0.f);
}
__global__ __launch_bounds__(256) void pack_gateB(const float* __restrict__ p, u16* __restrict__ o)
{
    int t = blockIdx.x * 256 + threadIdx.x;
    if (t >= 40 * 304 * 8) return;
    int j = t & 7, n = (t >> 3) % 304, kt = t / (304 * 8);
    int k = kt * 8 + j;
    o[t] = f2bf((k < 300 && n < 300) ? p[k * 300 + n] : 0.f);
}

// ---- MFMA epilogue: 32 rows/block, 512 threads (8 waves) ----
// pa GEMM: 8 tiles (2 row-tiles x 4 col-tiles), one per wave.
// pf/gate: 2 row-tiles x 19 col-tiles; wave w -> row tile w>>2, col tiles (w&3)+4t.
// layouts (16x16x32 bf16): A[m=lane&15][k=quad*8+j]; C/D col=lane&15,row=quad*4+reg
__global__ __launch_bounds__(512, 6) void epilogue_mfma(
    const float* __restrict__ outbuf, const u16* __restrict__ PT, const u16* __restrict__ PB,
    const u16* __restrict__ GB, const float* __restrict__ pn, const float* __restrict__ bias,
    float* __restrict__ dout, float alpha, int accumulate)
{
    __shared__ u16 s_h[32][324];   // hi bf16 plane: out, later pf
    __shared__ u16 s_l[32][324];   // lo bf16 plane
    __shared__ float s_pa[32][68];
    __shared__ float s_rn[32], s_pinv[32];

    const int tid = threadIdx.x;
    const int w = tid >> 6, quad = (tid >> 4) & 3, n15 = tid & 15;
    const int wr = w >> 2, wc = w & 3;
    const size_t rowBase = (size_t)blockIdx.x * 32;

    // zero pad cols 300..323
    for (int x = tid; x < 32 * 24; x += 512) {
        int r = x / 24, c = 300 + (x - (x / 24) * 24);
        s_h[r][c] = 0; s_l[r][c] = 0;
    }
    // main staging: float4 loads, 8B LDS writes per plane
    for (int x = tid; x < 32 * 75; x += 512) {
        int r = x / 75, c4 = x - r * 75, c = c4 * 4;
        float4 v = *(const float4*)(outbuf + (rowBase + r) * DOUTK + c);
        u16 h0, l0, h1, l1, h2, l2v, h3, l3;
        split_hl(v.x, h0, l0);
        split_hl(v.y, h1, l1);
        split_hl(v.z, h2, l2v);
        split_hl(v.w, h3, l3);
        u16x4 hv = {h0, h1, h2, h3};
        u16x4 lv = {l0, l1, l2v, l3};
        *(u16x4*)&s_h[r][c] = hv;
        *(u16x4*)&s_l[r][c] = lv;
    }
    __syncthreads();

    { // row inverse norms: 32 rows x 16 lanes = all 512 threads
        int r = tid >> 4, l = tid & 15;
        float s = 0.f;
        for (int i = l; i < 300; i += 16) {
            float v = bf2f(s_h[r][i]) + bf2f(s_l[r][i]);
            s += v * v;
        }
#pragma unroll
        for (int m = 8; m; m >>= 1) s += __shfl_xor(s, m, 64);
        if (l == 0) s_rn[r] = 1.f / fmaxf(sqrtf(s), 1e-12f);
    }
    __syncthreads();

    // ---- pa logits: D[32x64] = out @ proxy^T, 8 tiles over 8 waves ----
    f32x4 accp = {0.f, 0.f, 0.f, 0.f};
    {
        const int arow = wr * 16 + n15;
        for (int kk = 0; kk < 10; ++kk) {
            short8 ah = *(const short8*)&s_h[arow][kk * 32 + quad * 8];
            short8 al = *(const short8*)&s_l[arow][kk * 32 + quad * 8];
            short8 b = *(const short8*)(PT + (((kk * 4 + quad) * 64) + (wc * 16 + n15)) * 8);
            accp = __builtin_amdgcn_mfma_f32_16x16x32_bf16(ah, b, accp, 0, 0, 0);
            accp = __builtin_amdgcn_mfma_f32_16x16x32_bf16(al, b, accp, 0, 0, 0);
        }
    }
    {
        int col = wc * 16 + n15;
        float pnc = pn[col];
#pragma unroll
        for (int g = 0; g < 4; ++g) {
            int row = wr * 16 + quad * 4 + g;
            s_pa[row][col] = __expf(accp[g] * s_rn[row] * pnc);
        }
    }
    __syncthreads();
    { // softmax denominators: 32 rows x 16 lanes
        int r = tid >> 4, l = tid & 15;
        float s = s_pa[r][l] + s_pa[r][l + 16] + s_pa[r][l + 32] + s_pa[r][l + 48];
#pragma unroll
        for (int m = 8; m; m >>= 1) s += __shfl_xor(s, m, 64);
        if (l == 0) s_pinv[r] = 1.f / s;
    }
    __syncthreads();

    // ---- pf: T[32x304] = pa_raw @ proxy; pf = out - T*pinv, in place ----
    f32x4 accf[5];
#pragma unroll
    for (int t = 0; t < 5; ++t) accf[t] = (f32x4){0.f, 0.f, 0.f, 0.f};
    for (int kk = 0; kk < 2; ++kk) {
        short8 ah, al;
        {
            const float* srcp = &s_pa[wr * 16 + n15][kk * 32 + quad * 8];
#pragma unroll
            for (int j = 0; j < 8; ++j) {
                float x = srcp[j];
                u32 h = __float_as_uint(x) >> 16;
                float hf = __uint_as_float(h << 16);
                ah[j] = (short)h;
                al[j] = (short)(__float_as_uint(x - hf) >> 16);
            }
        }
#pragma unroll
        for (int t = 0; t < 5; ++t) {
            int nt = wc + 4 * t;
            if (nt < 19) {
                short8 b = *(const short8*)(PB + (((kk * 4 + quad) * 304) + (nt * 16 + n15)) * 8);
                accf[t] = __builtin_amdgcn_mfma_f32_16x16x32_bf16(ah, b, accf[t], 0, 0, 0);
                accf[t] = __builtin_amdgcn_mfma_f32_16x16x32_bf16(al, b, accf[t], 0, 0, 0);
            }
        }
    }
#pragma unroll
    for (int t = 0; t < 5; ++t) {
        int nt = wc + 4 * t;
        if (nt < 19) {
            int col = nt * 16 + n15;
#pragma unroll
            for (int g = 0; g < 4; ++g) {
                int row = wr * 16 + quad * 4 + g;
                float ov = bf2f(s_h[row][col]) + bf2f(s_l[row][col]);
                float v = ov - accf[t][g] * s_pinv[row];
                u16 hh, ll;
                split_hl(v, hh, ll);
                s_h[row][col] = hh;
                s_l[row][col] = ll;
            }
        }
    }
    __syncthreads();

    // ---- gate: Z[32x304] = pf @ gate_k ----
    f32x4 accg[5];
#pragma unroll
    for (int t = 0; t < 5; ++t) accg[t] = (f32x4){0.f, 0.f, 0.f, 0.f};
    {
        const int arow = wr * 16 + n15;
        for (int kk = 0; kk < 10; ++kk) {
            short8 ah = *(const short8*)&s_h[arow][kk * 32 + quad * 8];
            short8 al = *(const short8*)&s_l[arow][kk * 32 + quad * 8];
#pragma unroll
            for (int t = 0; t < 5; ++t) {
                int nt = wc + 4 * t;
                if (nt < 19) {
                    short8 b = *(const short8*)(GB + (((kk * 4 + quad) * 304) + (nt * 16 + n15)) * 8);
                    accg[t] = __builtin_amdgcn_mfma_f32_16x16x32_bf16(ah, b, accg[t], 0, 0, 0);
                    accg[t] = __builtin_amdgcn_mfma_f32_16x16x32_bf16(al, b, accg[t], 0, 0, 0);
                }
            }
        }
    }
    // ---- gated mix + store: res = pv + gate * (accf * pinv) ----
#pragma unroll
    for (int t = 0; t < 5; ++t) {
        int nt = wc + 4 * t;
        if (nt < 19) {
            int col = nt * 16 + n15;
            if (col < 300) {
                float bb = bias[col];
#pragma unroll
                for (int g = 0; g < 4; ++g) {
                    int row = wr * 16 + quad * 4 + g;
                    float z = accg[t][g] + bb;
                    float gg = 1.f / (1.f + __expf(-z));
                    float pv = bf2f(s_h[row][col]) + bf2f(s_l[row][col]);
                    float res = (pv + gg * accf[t][g] * s_pinv[row]) * alpha;
                    float* o = dout + (rowBase + row) * 600 + col;
                    if (accumulate) res += *o;
                    *o = res;
                }
            }
        }
    }
}

extern "C" void kernel_launch(void* const* d_in, const int* in_sizes, int n_in,
                              void* d_out, int out_size, void* d_ws, size_t ws_size,
                              hipStream_t stream)
{
    const int*   adj      = (const int*)d_in[0];
    const int*   r_index  = (const int*)d_in[1];
    const float* r_val    = (const float*)d_in[2];
    const int*   t_index  = (const int*)d_in[3];
    const int*   ent_adj  = (const int*)d_in[4];
    const int*   rel_adj  = (const int*)d_in[5];
    const int*   time_adj = (const int*)d_in[6];
    const float* ent_emb  = (const float*)d_in[7];
    const float* rel_emb  = (const float*)d_in[8];
    const float* time_emb = (const float*)d_in[9];
    const float* e_attn   = (const float*)d_in[10];
    const float* e_gate   = (const float*)d_in[11];
    const float* e_proxy  = (const float*)d_in[12];
    const float* e_bias   = (const float*)d_in[13];
    const float* r_attn   = (const float*)d_in[14];
    const float* r_gate   = (const float*)d_in[15];
    const float* r_proxy  = (const float*)d_in[16];
    const float* r_bias   = (const float*)d_in[17];
    float* out = (float*)d_out;

    char* ws = (char*)d_ws;
    size_t off = 0;
    auto alloc = [&](size_t bytes) { void* p = ws + off; off += (bytes + 255) & ~255ULL; return p; };
    u16* rels     = (u16*)alloc((size_t)EE * DDIM * 2);       // 80 MB
    float* outbuf = (float*)alloc((size_t)NN * DOUTK * 4);    // 120 MB (also r-CSR scratch while dead)
    float* attE0  = (float*)alloc((size_t)EE * 4);
    float* attE1  = (float*)alloc((size_t)EE * 4);
    float* attR0  = (float*)alloc((size_t)EE * 4);
    float* attR1  = (float*)alloc((size_t)EE * 4);
    float* denE0  = (float*)alloc((size_t)NN * 4);
    float* denE1  = (float*)alloc((size_t)NN * 4);
    float* denR0  = (float*)alloc((size_t)NN * 4);
    float* denR1  = (float*)alloc((size_t)NN * 4);
    int* adjcnt   = (int*)alloc((size_t)NN * 4);
    int* abase    = (int*)alloc((size_t)NN * 4);
    int* acur     = (int*)alloc((size_t)NN * 4);
    int* ecol     = (int*)alloc((size_t)EE * 4);
    int* epos     = (int*)alloc((size_t)EE * 4);
    int* fcnt     = (int*)alloc((size_t)NN * 4);
    int* fbase    = (int*)alloc((size_t)NN * 4);
    int* fcur     = (int*)alloc((size_t)NN * 4);
    int* fcol     = (int*)alloc((size_t)ADJK * 4);
    int* ctr      = (int*)alloc(256);
    float* pnE    = (float*)alloc(64 * 4);
    float* pnR    = (float*)alloc(64 * 4);
    u16* PT_E     = (u16*)alloc(40 * 64 * 8 * 2);
    u16* PT_R     = (u16*)alloc(40 * 64 * 8 * 2);
    u16* PB_E     = (u16*)alloc(8 * 304 * 8 * 2);
    u16* PB_R     = (u16*)alloc(8 * 304 * 8 * 2);
    u16* GB_E     = (u16*)alloc(40 * 304 * 8 * 2);
    u16* GB_R     = (u16*)alloc(40 * 304 * 8 * 2);

    // r/t sparse-index CSR aliased onto outbuf (outbuf is dead whenever rels is (re)built)
    int*   rcnt  = (int*)outbuf;          // EE ints
    int*   rbase = rcnt + EE;             // EE
    int*   rcur  = rbase + EE;            // EE
    int*   rk    = rcur + EE;             // NNZK
    float* rv    = (float*)(rk + NNZK);   // NNZK   -> total 11.2 MB << 120 MB

    proxy_norms<<<1, 64, 0, stream>>>(e_proxy, pnE);
    proxy_norms<<<1, 64, 0, stream>>>(r_proxy, pnR);
    pack_proxyT<<<80, 256, 0, stream>>>(e_proxy, PT_E);
    pack_proxyT<<<80, 256, 0, stream>>>(r_proxy, PT_R);
    pack_proxyB<<<76, 256, 0, stream>>>(e_proxy, PB_E);
    pack_proxyB<<<76, 256, 0, stream>>>(r_proxy, PB_R);
    pack_gateB<<<380, 256, 0, stream>>>(e_gate, GB_E);
    pack_gateB<<<380, 256, 0, stream>>>(r_gate, GB_R);

    // ---- adj CSR (shared by all encoders), built once ----
    hipMemsetAsync(adjcnt, 0, (size_t)NN * 4, stream);
    hipMemsetAsync(ctr, 0, 4, stream);
    k_count<<<(EE + 255) / 256, 256, 0, stream>>>(adj, adjcnt, EE, NN);
    k_alloc<<<(NN + 255) / 256, 256, 0, stream>>>(adjcnt, abase, acur, ctr, NN);
    k_fill<<<(EE + 255) / 256, 256, 0, stream>>>(adj, nullptr, acur, ecol, nullptr, epos, EE, NN);

    auto build_rels = [&](const int* sp, const float* emb, int kMax,
                          const float* attnA, float* aA0, float* aA1, float* dA0, float* dA1,
                          const float* attnB, float* aB0, float* aB1, float* dB0, float* dB1) {
        hipMemsetAsync(rcnt, 0, (size_t)EE * 4, stream);
        hipMemsetAsync(ctr, 0, 4, stream);
        hipMemsetAsync(dA0, 0, (size_t)NN * 4, stream);
        hipMemsetAsync(dA1, 0, (size_t)NN * 4, stream);
        if (attnB) {
            hipMemsetAsync(dB0, 0, (size_t)NN * 4, stream);
            hipMemsetAsync(dB1, 0, (size_t)NN * 4, stream);
        }
        k_count<<<(NNZK + 255) / 256, 256, 0, stream>>>(sp, rcnt, NNZK, EE);
        k_alloc<<<(EE + 255) / 256, 256, 0, stream>>>(rcnt, rbase, rcur, ctr, EE);
        k_fill<<<(NNZK + 255) / 256, 256, 0, stream>>>(sp, r_val, rcur, rk, rv, nullptr, NNZK, EE);
        rels_build<<<(EE + 7) / 8, 256, 0, stream>>>(rbase, rcnt, rk, rv, epos, adj, emb, rels,
                                                     attnA, aA0, aA1, dA0, dA1,
                                                     attnB, aB0, aB1, dB0, dB1, kMax, EE);
        // fold 1/den into att (removes per-edge divide from mp_layer)
        att_fold<<<(NN + 255) / 256, 256, 0, stream>>>(abase, adjcnt,
                                                       aA0, aA1, dA0, dA1,
                                                       aB0, aB1, dB0, dB1, NN);
    };

    struct Enc {
        const int* fadj; const float* femb; int colMax;
        const float* a0; const float* a1;
        const u16* PT; const u16* PB; const u16* GB; const float* pn; const float* bias;
        int dcol; float alpha; int accum;
    };
    Enc encs[3] = {
        { ent_adj,  ent_emb,  NN,   attE0, attE1, PT_E, PB_E, GB_E, pnE, e_bias,   0, 1.0f, 0 },
        { rel_adj,  rel_emb,  2000, attR0, attR1, PT_R, PB_R, GB_R, pnR, r_bias, 300, 0.5f, 0 },
        { time_adj, time_emb, 1000, attE0, attE1, PT_E, PB_E, GB_E, pnE, e_bias, 300, 0.5f, 1 },
    };

    // relsR: used by enc 0 (e_attn set) and enc 1 (r_attn set)
    build_rels(r_index, rel_emb, 2000,
               e_attn, attE0, attE1, denE0, denE1,
               r_attn, attR0, attR1, denR0, denR1);
    for (int c = 0; c < 3; ++c) {
        if (c == 2) {
            // relsT replaces relsR (outbuf dead here); e_attn set reused for T
            build_rels(t_index, time_emb, 1000,
                       e_attn, attE0, attE1, denE0, denE1,
                       nullptr, nullptr, nullptr, nullptr, nullptr);
        }
        const Enc& e = encs[c];

        // feature-adjacency CSR for this encoder
        hipMemsetAsync(fcnt, 0, (size_t)NN * 4, stream);
        hipMemsetAsync(ctr, 0, 4, stream);
        k_count<<<(ADJK + 255) / 256, 256, 0, stream>>>(e.fadj, fcnt, ADJK, NN);
        k_alloc<<<(NN + 255) / 256, 256, 0, stream>>>(fcnt, fbase, fcur, ctr, NN);
        k_fill<<<(ADJK + 255) / 256, 256, 0, stream>>>(e.fadj, nullptr, fcur, fcol, nullptr, nullptr, ADJK, NN);

        feat_gather<<<(NN + 7) / 8, 256, 0, stream>>>(fbase, fcnt, fcol, e.femb, outbuf, e.colMax, NN);
        mp_layer<<<(NN + 3) / 4, 256, 0, stream>>>(abase, adjcnt, ecol, rels, e.a0,
                                                   outbuf, outbuf + DDIM, NN);
        mp_layer<<<(NN + 3) / 4, 256, 0, stream>>>(abase, adjcnt, ecol, rels, e.a1,
                                                   outbuf + DDIM, outbuf + 2 * DDIM, NN);
        epilogue_mfma<<<NN / 32, 512, 0, stream>>>(outbuf, e.PT, e.PB, e.GB, e.pn, e.bias,
                                                   out + e.dcol, e.alpha, e.accum);
    }
}